// Round 1
// 180.025 us; speedup vs baseline: 1.0240x; 1.0240x over previous
//
#include <hip/hip_runtime.h>
#include <math.h>

// Problem constants (from reference)
#define KK     500   // info bits
#define MM     500   // parity checks
#define NNODES 1000  // N = K + M variable nodes
#define NSYM   250   // N / BPS
#define NITERS 5
#define MAXVDEG 4    // info vars degree exactly 3 (row weight of P), parity vars 1
#define EMAX   2048  // E = 2000 edges
#define TB     256
#define LTB    64    // k_lmmse block size (1 wave) for scheduling granularity

// ---------------- setup: graph build + bit packing + bf output -------------
// Slot layout per check c: info edges in coff[c]..coff[c+1]-2 (atomic order),
// the single parity edge (var >= KK) pinned to coff[c+1]-1 so the BP product
// loop can skip it and use a register-cached constant instead.
__global__ void __launch_bounds__(512)
k_setup(const int* __restrict__ cn, const int* __restrict__ vn, int E,
        const float* __restrict__ ebno, const int* __restrict__ P,
        const int* __restrict__ b, int ncw,
        int* __restrict__ cinfo, int* __restrict__ vlist, int* __restrict__ coff,
        double* __restrict__ nobuf, unsigned* __restrict__ Ppack,
        unsigned* __restrict__ bpack, float* __restrict__ out, int packBlocks) {
  __shared__ int sdeg[512];
  __shared__ int ssc[512];
  __shared__ int scur[512];
  __shared__ int svc[NNODES];
  int tid = threadIdx.x;
  int bx = blockIdx.x;

  if (bx == 0) {
    sdeg[tid] = 0;
    for (int n = tid; n < NNODES; n += 512) svc[n] = 0;
    __syncthreads();
    for (int e = tid; e < E; e += 512) atomicAdd(&sdeg[cn[e]], 1);
    __syncthreads();
    int v = sdeg[tid];
    ssc[tid] = v;
    __syncthreads();
    for (int o = 1; o < 512; o <<= 1) {
      int x = (tid >= o) ? ssc[tid - o] : 0;
      __syncthreads();
      ssc[tid] += x;
      __syncthreads();
    }
    int excl = ssc[tid] - v;
    scur[tid] = excl;
    if (tid < MM) {
      coff[tid] = excl;
      if (tid == MM - 1) coff[MM] = ssc[tid];
    }
    __syncthreads();
    for (int e = tid; e < E; e += 512) {
      int c = cn[e], n = vn[e];
      int slot;
      if (n >= KK) {
        slot = ssc[c] - 1;               // parity edge -> last slot of check c
      } else {
        slot = atomicAdd(&scur[c], 1);   // info edges fill coff[c]..coff[c+1]-2
      }
      cinfo[slot] = (c << 16) | n;
      if (n < KK) {
        int t = atomicAdd(&svc[n], 1);
        if (t < MAXVDEG) vlist[n * MAXVDEG + t] = slot;
      }
    }
    if (tid == 0) {
      double no = 1.0 / (pow(10.0, (double)ebno[0] * 0.1) * 2.0);  // BPS*RATE = 2
      nobuf[0] = no;
      nobuf[1] = sqrt(no * 0.5);
    }
    return;
  }

  if (bx <= packBlocks) {
    int id = (bx - 1) * 512 + tid;
    if (id < MM * 16) {
      int j = id >> 4, w = id & 15;
      unsigned word = 0u;
      int base = w * 32;
      for (int bit = 0; bit < 32; ++bit) {
        int i = base + bit;
        if (i < KK && P[i * MM + j] != 0) word |= (1u << bit);
      }
      Ppack[j * 16 + w] = word;
    } else {
      int id2 = id - MM * 16;
      if (id2 < ncw * 16) {
        int cw = id2 >> 4, w = id2 & 15;
        unsigned word = 0u;
        int base = w * 32;
        for (int bit = 0; bit < 32; ++bit) {
          int i = base + bit;
          if (i < KK && b[cw * KK + i] != 0) word |= (1u << bit);
        }
        bpack[cw * 16 + w] = word;
      }
    }
    return;
  }

  int id = (bx - 1 - packBlocks) * 512 + tid;
  if (id < ncw * KK) out[id] = (float)b[id];
}

// ---------------- 16-QAM constellation (fp32 TX symbol) --------------------
__device__ __forceinline__ void qam_pointf(int p, float& re, float& im) {
  const float s = 0.31622776601683794f;  // 1/sqrt(10)
  int b0 = (p >> 3) & 1, b1 = (p >> 2) & 1, b2 = (p >> 1) & 1, b3 = p & 1;
  re = (float)((1 - 2 * b0) * (2 - (1 - 2 * b2))) * s;
  im = (float)((1 - 2 * b1) * (2 - (1 - 2 * b3))) * s;
}

// ---------------- channel + LMMSE + max-log LLR --------------------------
// Round-13: full fp32 chain.  Round-12 profile showed ~3.8 waves/SIMD of
// total work (T=250k) with VALUBusy 23% -> per-thread dependent-chain
// LATENCY sets runtime, and the chain was fp64 (2x issue cost, ~2x dep
// latency on gfx950).  The reference computes this entire block in
// complex64 (fp32) -- jnp.linalg.solve on complex64 -- so fp32 here is the
// same precision class as the reference itself.  1-dj is Sterbenz-exact in
// fp32 (dj in [0.5,1]), so the one cancellation-sensitive spot is safe.
__global__ void __launch_bounds__(LTB, 1)
k_lmmse(const float* __restrict__ h_re, const float* __restrict__ h_im,
        const float* __restrict__ n_re, const float* __restrict__ n_im,
        const double* __restrict__ nobuf,
        const unsigned* __restrict__ bpack, const unsigned* __restrict__ Ppack,
        float* __restrict__ Lch3, int T, int ncw) {
  int t = blockIdx.x * blockDim.x + threadIdx.x;
  if (t >= T) return;
  int bt = t / NSYM, s = t - bt * NSYM;

  float no = (float)nobuf[0];
  float sq = (float)nobuf[1];
  const float is2 = 0.70710678118654752f;  // 1/sqrt(2)

  float Hr[4][4], Hi[4][4];
  {
    const float4* hr4 = (const float4*)h_re;
    const float4* hi4 = (const float4*)h_im;
    #pragma unroll
    for (int i = 0; i < 4; ++i) {
      float4 a = hr4[t * 4 + i], c = hi4[t * 4 + i];
      Hr[i][0] = a.x * is2; Hr[i][1] = a.y * is2;
      Hr[i][2] = a.z * is2; Hr[i][3] = a.w * is2;
      Hi[i][0] = c.x * is2; Hi[i][1] = c.y * is2;
      Hi[i][2] = c.z * is2; Hi[i][3] = c.w * is2;
    }
  }

  // transmitted symbols: encode+map inline
  float xr[4], xi[4];
  #pragma unroll
  for (int ue = 0; ue < 4; ++ue) {
    const unsigned* bp = bpack + (bt * 4 + ue) * 16;
    int v = 0;
    #pragma unroll
    for (int k = 0; k < 4; ++k) {
      int n = 4 * s + k;
      int bit;
      if (n < KK) {
        bit = (bp[n >> 5] >> (n & 31)) & 1;
      } else {
        const unsigned* pp = Ppack + (n - KK) * 16;
        int cnt = 0;
        #pragma unroll
        for (int w = 0; w < 16; ++w) cnt += __popc(bp[w] & pp[w]);
        bit = cnt & 1;
      }
      v = (v << 1) | bit;  // MSB-first: weights 8,4,2,1
    }
    qam_pointf(v, xr[ue], xi[ue]);
  }

  // y = H x + w
  float yr[4], yi[4];
  {
    float4 wr = ((const float4*)n_re)[t];
    float4 wi = ((const float4*)n_im)[t];
    float wrv[4] = {wr.x, wr.y, wr.z, wr.w};
    float wiv[4] = {wi.x, wi.y, wi.z, wi.w};
    #pragma unroll
    for (int i = 0; i < 4; ++i) {
      float ar = wrv[i] * sq;
      float ai = wiv[i] * sq;
      #pragma unroll
      for (int j = 0; j < 4; ++j) {
        ar += Hr[i][j] * xr[j] - Hi[i][j] * xi[j];
        ai += Hr[i][j] * xi[j] + Hi[i][j] * xr[j];
      }
      yr[i] = ar; yi[i] = ai;
    }
  }

  // A = H H^H + no I, lower triangle, into scalars
  auto dotc = [&](int i, int j, float& ar, float& ai) {
    float r = 0.0f, m = 0.0f;
    #pragma unroll
    for (int k = 0; k < 4; ++k) {
      r += Hr[i][k] * Hr[j][k] + Hi[i][k] * Hi[j][k];
      m += Hi[i][k] * Hr[j][k] - Hr[i][k] * Hi[j][k];
    }
    ar = r; ai = m;
  };
  float a00, a11, a22, a33, dum;
  float a10r, a10i, a20r, a20i, a21r, a21i, a30r, a30i, a31r, a31i, a32r, a32i;
  dotc(0, 0, a00, dum);  a00 += no;
  dotc(1, 0, a10r, a10i);
  dotc(1, 1, a11, dum);  a11 += no;
  dotc(2, 0, a20r, a20i);
  dotc(2, 1, a21r, a21i);
  dotc(2, 2, a22, dum);  a22 += no;
  dotc(3, 0, a30r, a30i);
  dotc(3, 1, a31r, a31i);
  dotc(3, 2, a32r, a32i);
  dotc(3, 3, a33, dum);  a33 += no;

  // Cholesky in inverse-diagonal form: i_jj = rsqrt(d_jj); L_jj never formed.
  float i00 = rsqrtf(a00);
  float L10r = a10r * i00, L10i = a10i * i00;
  float L20r = a20r * i00, L20i = a20i * i00;
  float L30r = a30r * i00, L30i = a30i * i00;
  float d11 = a11 - (L10r * L10r + L10i * L10i);
  float i11 = rsqrtf(d11);
  float L21r = (a21r - (L20r * L10r + L20i * L10i)) * i11;
  float L21i = (a21i - (L20i * L10r - L20r * L10i)) * i11;
  float L31r = (a31r - (L30r * L10r + L30i * L10i)) * i11;
  float L31i = (a31i - (L30i * L10r - L30r * L10i)) * i11;
  float d22 = a22 - (L20r * L20r + L20i * L20i) - (L21r * L21r + L21i * L21i);
  float i22 = rsqrtf(d22);
  float L32r = (a32r - (L30r * L20r + L30i * L20i) - (L31r * L21r + L31i * L21i)) * i22;
  float L32i = (a32i - (L30i * L20r - L30r * L20i) - (L31i * L21r - L31r * L21i)) * i22;
  float d33 = a33 - (L30r * L30r + L30i * L30i) - (L31r * L31r + L31i * L31i)
                  - (L32r * L32r + L32i * L32i);
  float i33 = rsqrtf(d33);

  // forward solve: U = L^{-1} H (in place on H), v = L^{-1} y (in place on y)
  #pragma unroll
  for (int j = 0; j < 4; ++j) {
    float u0r = Hr[0][j] * i00,               u0i = Hi[0][j] * i00;
    float u1r = (Hr[1][j] - (L10r * u0r - L10i * u0i)) * i11;
    float u1i = (Hi[1][j] - (L10r * u0i + L10i * u0r)) * i11;
    float u2r = (Hr[2][j] - (L20r * u0r - L20i * u0i) - (L21r * u1r - L21i * u1i)) * i22;
    float u2i = (Hi[2][j] - (L20r * u0i + L20i * u0r) - (L21r * u1i + L21i * u1r)) * i22;
    float u3r = (Hr[3][j] - (L30r * u0r - L30i * u0i) - (L31r * u1r - L31i * u1i)
                          - (L32r * u2r - L32i * u2i)) * i33;
    float u3i = (Hi[3][j] - (L30r * u0i + L30i * u0r) - (L31r * u1i + L31i * u1r)
                          - (L32r * u2i + L32i * u2r)) * i33;
    Hr[0][j] = u0r; Hi[0][j] = u0i; Hr[1][j] = u1r; Hi[1][j] = u1i;
    Hr[2][j] = u2r; Hi[2][j] = u2i; Hr[3][j] = u3r; Hi[3][j] = u3i;
  }
  {
    float v0r = yr[0] * i00,               v0i = yi[0] * i00;
    float v1r = (yr[1] - (L10r * v0r - L10i * v0i)) * i11;
    float v1i = (yi[1] - (L10r * v0i + L10i * v0r)) * i11;
    float v2r = (yr[2] - (L20r * v0r - L20i * v0i) - (L21r * v1r - L21i * v1i)) * i22;
    float v2i = (yi[2] - (L20r * v0i + L20i * v0r) - (L21r * v1i + L21i * v1r)) * i22;
    float v3r = (yr[3] - (L30r * v0r - L30i * v0i) - (L31r * v1r - L31i * v1i)
                       - (L32r * v2r - L32i * v2i)) * i33;
    float v3i = (yi[3] - (L30r * v0i + L30i * v0r) - (L31r * v1i + L31i * v1r)
                       - (L32r * v2i + L32i * v2r)) * i33;
    yr[0] = v0r; yi[0] = v0i; yr[1] = v1r; yi[1] = v1i;
    yr[2] = v2r; yi[2] = v2i; yr[3] = v3r; yi[3] = v3i;
  }

  // fp32 16-QAM table
  const float PRT[16] = { 0.31622776601683794f, 0.31622776601683794f, 0.9486832980505138f, 0.9486832980505138f,
                          0.31622776601683794f, 0.31622776601683794f, 0.9486832980505138f, 0.9486832980505138f,
                         -0.31622776601683794f,-0.31622776601683794f,-0.9486832980505138f,-0.9486832980505138f,
                         -0.31622776601683794f,-0.31622776601683794f,-0.9486832980505138f,-0.9486832980505138f };
  const float PIT[16] = { 0.31622776601683794f, 0.9486832980505138f, 0.31622776601683794f, 0.9486832980505138f,
                         -0.31622776601683794f,-0.9486832980505138f,-0.31622776601683794f,-0.9486832980505138f,
                          0.31622776601683794f, 0.9486832980505138f, 0.31622776601683794f, 0.9486832980505138f,
                         -0.31622776601683794f,-0.9486832980505138f,-0.31622776601683794f,-0.9486832980505138f };

  float llr[4][4];  // [bit k][ue j]
  #pragma unroll
  for (int j = 0; j < 4; ++j) {
    float dj = 0.0f, rr = 0.0f, ri = 0.0f;
    #pragma unroll
    for (int i = 0; i < 4; ++i) {
      dj += Hr[i][j] * Hr[i][j] + Hi[i][j] * Hi[i][j];
      rr += Hr[i][j] * yr[i] + Hi[i][j] * yi[i];
      ri += Hr[i][j] * yi[i] - Hi[i][j] * yr[i];
    }
    // 1 - dj is Sterbenz-exact for dj in [0.5, 1]; d < 1 - no/lambda strictly.
    float rdj = __fdividef(1.0f, dj);
    float xhr = rr * rdj, xhi = ri * rdj;
    float gap = 1.0f - dj;
    float inoe = __fdividef(dj, fmaxf(gap, dj * 1e-12f));

    float m0[4] = {-1e30f, -1e30f, -1e30f, -1e30f};
    float m1[4] = {-1e30f, -1e30f, -1e30f, -1e30f};
    #pragma unroll
    for (int p = 0; p < 16; ++p) {
      float dr = xhr - PRT[p], di = xhi - PIT[p];
      float met = -(dr * dr + di * di) * inoe;
      #pragma unroll
      for (int k = 0; k < 4; ++k) {
        if ((p >> (3 - k)) & 1) m1[k] = fmaxf(m1[k], met);
        else                    m0[k] = fmaxf(m0[k], met);
      }
    }
    #pragma unroll
    for (int k = 0; k < 4; ++k) llr[k][j] = m0[k] - m1[k];
  }

  // store: plane 0 = ue{0,1}, plane 1 = ue{2,3}
  float2* pl0 = (float2*)(Lch3 + (size_t)bt * (NNODES * 4));
  float2* pl1 = pl0 + NNODES;
  #pragma unroll
  for (int k = 0; k < 4; ++k) {
    int node = 4 * s + k;
    pl0[node] = make_float2(llr[k][0], llr[k][1]);
    pl1[node] = make_float2(llr[k][2], llr[k][3]);
  }
}

// ---------------- fused LDS-resident BP decoder, 2 codewords / block --------
// Division-free pass-1: (A-B)/(A+B) invariant under common scale; factor
// pairs scaled by their own t (a' = t + Pc, b' = t - Pc).  Parity edges
// (one per check, constant t) factored into a register (qpar); product loop
// runs [beg, end-1).
__device__ __forceinline__ float tanh_half(float m) {
  float mc = fminf(fmaxf(m, -19.8f), 19.8f);
  float e = __expf(mc);
  float t = 1.0f - __fdividef(2.0f, e + 1.0f);
  return (t >= 0.0f) ? fmaxf(t, 1e-7f) : fminf(t, -1e-7f);
}
__device__ __forceinline__ float pclip(float P, float t) {
  // t * clip(P/t, +-0.999999), computed without dividing
  return copysignf(fminf(fabsf(P), 0.999999f * fabsf(t)), P);
}
__device__ __forceinline__ float tfloor(float t) {
  return (t >= 0.0f) ? fmaxf(t, 1e-7f) : fminf(t, -1e-7f);
}
__device__ __forceinline__ float atanh2c(float P, float t) {
  float r = __fdividef(P, t);
  r = fminf(fmaxf(r, -0.999999f), 0.999999f);
  return __logf(__fdividef(1.0f + r, 1.0f - r));
}

__global__ void __launch_bounds__(256) k_bp(const float* __restrict__ Lch3,
                                            const int* __restrict__ vlist,
                                            const int* __restrict__ coff,
                                            const int* __restrict__ cinfo,
                                            float* __restrict__ out, int E, int ncw) {
  __shared__ float2 sT[EMAX];   // tanh(v2c/2) per info-edge slot (16 KB)
  __shared__ float2 sP[512];    // per-check product of tanh (4 KB)

  int tid = threadIdx.x;
  int pairId = blockIdx.x;  // = bt*2 + plane; codewords 2*pairId, 2*pairId+1

  const float2* src = (const float2*)(Lch3 + (size_t)pairId * (NNODES * 2));

  // own info-node state in registers
  float2 Ln[2], En[2];
  int pk0[2], pk1[2], pk2[2]; bool iok[2];
  #pragma unroll
  for (int i = 0; i < 2; ++i) {
    int n = tid + TB * i;
    iok[i] = n < KK;
    Ln[i] = make_float2(0.f, 0.f);
    En[i] = make_float2(1.f, 1.f);
    pk0[i] = pk1[i] = pk2[i] = 0;
    if (iok[i]) {
      float2 L = src[n];
      Ln[i] = L;
      En[i] = make_float2(__expf(fminf(fmaxf(L.x, -55.f), 55.f)),
                          __expf(fminf(fmaxf(L.y, -55.f), 55.f)));
      int s0 = vlist[n * MAXVDEG], s1 = vlist[n * MAXVDEG + 1], s2 = vlist[n * MAXVDEG + 2];
      pk0[i] = (cinfo[s0] & 0xffff0000) | s0;
      pk1[i] = (cinfo[s1] & 0xffff0000) | s1;
      pk2[i] = (cinfo[s2] & 0xffff0000) | s2;
    }
  }
  // per-check constant: tanh of the parity-node LLR (check c <-> parity var KK+c)
  float2 qpar0, qpar1;
  {
    float2 Lp0 = src[KK + tid];
    qpar0 = make_float2(tanh_half(Lp0.x), tanh_half(Lp0.y));
  }
  bool c1ok = (tid + TB) < MM;
  if (c1ok) {
    float2 Lp1 = src[KK + tid + TB];
    qpar1 = make_float2(tanh_half(Lp1.x), tanh_half(Lp1.y));
  } else {
    qpar1 = make_float2(1.f, 1.f);
  }
  int beg0 = coff[tid], end0 = coff[tid + 1];
  int beg1 = c1ok ? coff[tid + TB] : 0;
  int end1 = c1ok ? coff[tid + TB + 1] : 0;
  // no barrier needed: first sT reads happen in pass 2, after the in-loop barrier

  for (int it = 0; it < NITERS; ++it) {
    // ---- pass 1: info-node var update ----
    if (it == 0) {
      #pragma unroll
      for (int i = 0; i < 2; ++i) {
        if (iok[i]) {
          float2 t = make_float2(tanh_half(Ln[i].x), tanh_half(Ln[i].y));
          sT[pk0[i] & 0xffff] = t;
          sT[pk1[i] & 0xffff] = t;
          sT[pk2[i] & 0xffff] = t;
        }
      }
    } else {
      #pragma unroll
      for (int i = 0; i < 2; ++i) {
        if (iok[i]) {
          int s0 = pk0[i] & 0xffff, c0 = ((unsigned)pk0[i]) >> 16;
          int s1 = pk1[i] & 0xffff, c1 = ((unsigned)pk1[i]) >> 16;
          int s2 = pk2[i] & 0xffff, c2 = ((unsigned)pk2[i]) >> 16;
          float2 P0 = sP[c0], P1 = sP[c1], P2 = sP[c2];
          float2 t0 = sT[s0], t1 = sT[s1], t2 = sT[s2];
          // lane x
          float p0 = pclip(P0.x, t0.x), p1 = pclip(P1.x, t1.x), p2 = pclip(P2.x, t2.x);
          float a0 = t0.x + p0, a1 = t1.x + p1, a2 = t2.x + p2;
          float b0 = t0.x - p0, b1 = t1.x - p1, b2 = t2.x - p2;
          float Ex = En[i].x;
          float A0 = Ex * (a1 * a2), A1 = Ex * (a0 * a2), A2 = Ex * (a0 * a1);
          float B0 = b1 * b2,        B1 = b0 * b2,        B2 = b0 * b1;
          float n0x = tfloor(__fdividef(A0 - B0, A0 + B0));
          float n1x = tfloor(__fdividef(A1 - B1, A1 + B1));
          float n2x = tfloor(__fdividef(A2 - B2, A2 + B2));
          // lane y
          float q0 = pclip(P0.y, t0.y), q1 = pclip(P1.y, t1.y), q2 = pclip(P2.y, t2.y);
          float c0a = t0.y + q0, c1a = t1.y + q1, c2a = t2.y + q2;
          float d0b = t0.y - q0, d1b = t1.y - q1, d2b = t2.y - q2;
          float Ey = En[i].y;
          float C0 = Ey * (c1a * c2a), C1 = Ey * (c0a * c2a), C2 = Ey * (c0a * c1a);
          float D0 = d1b * d2b,        D1 = d0b * d2b,        D2 = d0b * d1b;
          float n0y = tfloor(__fdividef(C0 - D0, C0 + D0));
          float n1y = tfloor(__fdividef(C1 - D1, C1 + D1));
          float n2y = tfloor(__fdividef(C2 - D2, C2 + D2));
          sT[s0] = make_float2(n0x, n0y);
          sT[s1] = make_float2(n1x, n1y);
          sT[s2] = make_float2(n2x, n2y);
        }
      }
    }
    __syncthreads();
    // ---- pass 2: per-check products (parity factor from register) ----
    {
      float px = qpar0.x, py = qpar0.y;
      for (int e = beg0; e < end0 - 1; ++e) { float2 tt = sT[e]; px *= tt.x; py *= tt.y; }
      sP[tid] = make_float2(px, py);
      if (c1ok) {
        float qx = qpar1.x, qy = qpar1.y;
        for (int e = beg1; e < end1 - 1; ++e) { float2 tt = sT[e]; qx *= tt.x; qy *= tt.y; }
        sP[tid + TB] = make_float2(qx, qy);
      }
    }
    __syncthreads();
  }

  // ---- decide: additive log form (once) ----
  int cw0 = pairId * 2;
  float* o0 = out + (size_t)ncw * KK + (size_t)cw0 * KK;
  float* o1 = o0 + KK;
  #pragma unroll
  for (int i = 0; i < 2; ++i) {
    if (iok[i]) {
      int n = tid + TB * i;
      int s0 = pk0[i] & 0xffff, c0 = ((unsigned)pk0[i]) >> 16;
      int s1 = pk1[i] & 0xffff, c1 = ((unsigned)pk1[i]) >> 16;
      int s2 = pk2[i] & 0xffff, c2 = ((unsigned)pk2[i]) >> 16;
      float2 P0 = sP[c0], P1 = sP[c1], P2 = sP[c2];
      float2 t0 = sT[s0], t1 = sT[s1], t2 = sT[s2];
      float2 L = Ln[i];
      float ax = L.x + atanh2c(P0.x, t0.x) + atanh2c(P1.x, t1.x) + atanh2c(P2.x, t2.x);
      float ay = L.y + atanh2c(P0.y, t0.y) + atanh2c(P1.y, t1.y) + atanh2c(P2.y, t2.y);
      o0[n] = (ax < 0.0f) ? 1.0f : 0.0f;
      o1[n] = (ay < 0.0f) ? 1.0f : 0.0f;
    }
  }
}

// ---------------- launcher ----------------
extern "C" void kernel_launch(void* const* d_in, const int* in_sizes, int n_in,
                              void* d_out, int out_size, void* d_ws, size_t ws_size,
                              hipStream_t stream) {
  const float* ebno = (const float*)d_in[1];
  const int*   b    = (const int*)d_in[2];
  const int*   P    = (const int*)d_in[3];
  const int*   cn   = (const int*)d_in[4];
  const int*   vn   = (const int*)d_in[5];
  const float* h_re = (const float*)d_in[6];
  const float* h_im = (const float*)d_in[7];
  const float* nre  = (const float*)d_in[8];
  const float* nim  = (const float*)d_in[9];
  float* out = (float*)d_out;

  int E     = in_sizes[4];
  int batch = in_sizes[2] / (4 * KK);
  int ncw   = batch * 4;
  int T     = batch * NSYM;

  char* ws = (char*)d_ws;
  size_t off = 0;
  auto alloc = [&](size_t bytes) -> void* {
    void* p = ws + off;
    off += (bytes + 255) & ~(size_t)255;
    return p;
  };
  float*    Lch3   = (float*)alloc((size_t)NNODES * ncw * 4);
  unsigned* Ppack  = (unsigned*)alloc((size_t)MM * 16 * 4);
  unsigned* bpack  = (unsigned*)alloc((size_t)ncw * 16 * 4);
  int*      coff   = (int*)alloc((size_t)(MM + 1) * 4);
  int*      cinfo  = (int*)alloc((size_t)EMAX * 4);
  int*      vlist  = (int*)alloc((size_t)NNODES * MAXVDEG * 4);
  double*   nobuf  = (double*)alloc(2 * 8);
  (void)ws_size; (void)n_in; (void)out_size;

  int packItems  = MM * 16 + ncw * 16;
  int packBlocks = (packItems + 511) / 512;
  int bfBlocks   = (ncw * KK + 511) / 512;
  int setupGrid  = 1 + packBlocks + bfBlocks;

  k_setup<<<dim3(setupGrid), dim3(512), 0, stream>>>(cn, vn, E, ebno, P, b, ncw,
                                                     cinfo, vlist, coff, nobuf,
                                                     Ppack, bpack, out, packBlocks);
  k_lmmse<<<dim3((T + LTB - 1) / LTB), dim3(LTB), 0, stream>>>(h_re, h_im, nre, nim, nobuf,
                                                               bpack, Ppack, Lch3, T, ncw);
  k_bp<<<dim3(ncw / 2), dim3(TB), 0, stream>>>(Lch3, vlist, coff, cinfo, out, E, ncw);
}

// Round 2
// 178.598 us; speedup vs baseline: 1.0322x; 1.0080x over previous
//
#include <hip/hip_runtime.h>
#include <math.h>

// Problem constants (from reference)
#define KK     500   // info bits
#define MM     500   // parity checks
#define NNODES 1000  // N = K + M variable nodes
#define NSYM   250   // N / BPS
#define NITERS 5
#define MAXVDEG 4    // info vars degree exactly 3 (row weight of P), parity vars 1
#define EMAX   2048  // E = 2000 edges
#define TB     256

// ---------------- setup: graph build + bit packing + bf output -------------
// Slot layout per check c: info edges in coff[c]..coff[c+1]-2 (atomic order),
// the single parity edge (var >= KK) pinned to coff[c+1]-1 so the BP product
// loop can skip it and use a register-cached constant instead.
__global__ void __launch_bounds__(512)
k_setup(const int* __restrict__ cn, const int* __restrict__ vn, int E,
        const float* __restrict__ ebno, const int* __restrict__ P,
        const int* __restrict__ b, int ncw,
        int* __restrict__ cinfo, int* __restrict__ vlist, int* __restrict__ coff,
        double* __restrict__ nobuf, unsigned* __restrict__ Ppack,
        unsigned* __restrict__ bpack, float* __restrict__ out, int packBlocks) {
  __shared__ int sdeg[512];
  __shared__ int ssc[512];
  __shared__ int scur[512];
  __shared__ int svc[NNODES];
  int tid = threadIdx.x;
  int bx = blockIdx.x;

  if (bx == 0) {
    sdeg[tid] = 0;
    for (int n = tid; n < NNODES; n += 512) svc[n] = 0;
    __syncthreads();
    for (int e = tid; e < E; e += 512) atomicAdd(&sdeg[cn[e]], 1);
    __syncthreads();
    int v = sdeg[tid];
    ssc[tid] = v;
    __syncthreads();
    for (int o = 1; o < 512; o <<= 1) {
      int x = (tid >= o) ? ssc[tid - o] : 0;
      __syncthreads();
      ssc[tid] += x;
      __syncthreads();
    }
    int excl = ssc[tid] - v;
    scur[tid] = excl;
    if (tid < MM) {
      coff[tid] = excl;
      if (tid == MM - 1) coff[MM] = ssc[tid];
    }
    __syncthreads();
    for (int e = tid; e < E; e += 512) {
      int c = cn[e], n = vn[e];
      int slot;
      if (n >= KK) {
        slot = ssc[c] - 1;               // parity edge -> last slot of check c
      } else {
        slot = atomicAdd(&scur[c], 1);   // info edges fill coff[c]..coff[c+1]-2
      }
      cinfo[slot] = (c << 16) | n;
      if (n < KK) {
        int t = atomicAdd(&svc[n], 1);
        if (t < MAXVDEG) vlist[n * MAXVDEG + t] = slot;
      }
    }
    if (tid == 0) {
      double no = 1.0 / (pow(10.0, (double)ebno[0] * 0.1) * 2.0);  // BPS*RATE = 2
      nobuf[0] = no;
      nobuf[1] = sqrt(no * 0.5);
    }
    return;
  }

  if (bx <= packBlocks) {
    int id = (bx - 1) * 512 + tid;
    if (id < MM * 16) {
      int j = id >> 4, w = id & 15;
      unsigned word = 0u;
      int base = w * 32;
      for (int bit = 0; bit < 32; ++bit) {
        int i = base + bit;
        if (i < KK && P[i * MM + j] != 0) word |= (1u << bit);
      }
      Ppack[j * 16 + w] = word;
    } else {
      int id2 = id - MM * 16;
      if (id2 < ncw * 16) {
        int cw = id2 >> 4, w = id2 & 15;
        unsigned word = 0u;
        int base = w * 32;
        for (int bit = 0; bit < 32; ++bit) {
          int i = base + bit;
          if (i < KK && b[cw * KK + i] != 0) word |= (1u << bit);
        }
        bpack[cw * 16 + w] = word;
      }
    }
    return;
  }

  int id = (bx - 1 - packBlocks) * 512 + tid;
  if (id < ncw * KK) out[id] = (float)b[id];
}

// ---------------- 16-QAM constellation (fp32 TX symbol) --------------------
__device__ __forceinline__ void qam_pointf(int p, float& re, float& im) {
  const float s = 0.31622776601683794f;  // 1/sqrt(10)
  int b0 = (p >> 3) & 1, b1 = (p >> 2) & 1, b2 = (p >> 1) & 1, b3 = p & 1;
  re = (float)((1 - 2 * b0) * (2 - (1 - 2 * b2))) * s;
  im = (float)((1 - 2 * b1) * (2 - (1 - 2 * b3))) * s;
}

// ---------------- BP helpers ----------------
__device__ __forceinline__ float tanh_half(float m) {
  float mc = fminf(fmaxf(m, -19.8f), 19.8f);
  float e = __expf(mc);
  float t = 1.0f - __fdividef(2.0f, e + 1.0f);
  return (t >= 0.0f) ? fmaxf(t, 1e-7f) : fminf(t, -1e-7f);
}
__device__ __forceinline__ float pclip(float P, float t) {
  return copysignf(fminf(fabsf(P), 0.999999f * fabsf(t)), P);
}
__device__ __forceinline__ float tfloor(float t) {
  return (t >= 0.0f) ? fmaxf(t, 1e-7f) : fminf(t, -1e-7f);
}
__device__ __forceinline__ float atanh2c(float P, float t) {
  float r = __fdividef(P, t);
  r = fminf(fmaxf(r, -0.999999f), 0.999999f);
  return __logf(__fdividef(1.0f + r, 1.0f - r));
}

// per-column forward solve + max-log demap, column index J compile-time.
// Uses i00..i33, L10..L32, Hr/Hi (unsolved), yr/yi (solved v = L^{-1}y).
#define SOLVE_DEMAP(J, Lout) {                                                          \
  float u0r = Hr[0][J] * i00,               u0i = Hi[0][J] * i00;                       \
  float u1r = (Hr[1][J] - (L10r * u0r - L10i * u0i)) * i11;                             \
  float u1i = (Hi[1][J] - (L10r * u0i + L10i * u0r)) * i11;                             \
  float u2r = (Hr[2][J] - (L20r * u0r - L20i * u0i) - (L21r * u1r - L21i * u1i)) * i22; \
  float u2i = (Hi[2][J] - (L20r * u0i + L20i * u0r) - (L21r * u1i + L21i * u1r)) * i22; \
  float u3r = (Hr[3][J] - (L30r * u0r - L30i * u0i) - (L31r * u1r - L31i * u1i)         \
                        - (L32r * u2r - L32i * u2i)) * i33;                             \
  float u3i = (Hi[3][J] - (L30r * u0i + L30i * u0r) - (L31r * u1i + L31i * u1r)         \
                        - (L32r * u2i + L32i * u2r)) * i33;                             \
  float dj = (u0r * u0r + u0i * u0i) + (u1r * u1r + u1i * u1i)                          \
           + (u2r * u2r + u2i * u2i) + (u3r * u3r + u3i * u3i);                         \
  float rr = (u0r * yr[0] + u0i * yi[0]) + (u1r * yr[1] + u1i * yi[1])                  \
           + (u2r * yr[2] + u2i * yi[2]) + (u3r * yr[3] + u3i * yi[3]);                 \
  float ri = (u0r * yi[0] - u0i * yr[0]) + (u1r * yi[1] - u1i * yr[1])                  \
           + (u2r * yi[2] - u2i * yr[2]) + (u3r * yi[3] - u3i * yr[3]);                 \
  float rdj = __fdividef(1.0f, dj);                                                    \
  float xhr = rr * rdj, xhi = ri * rdj;                                                \
  float gap = 1.0f - dj;                                                               \
  float inoe = __fdividef(dj, fmaxf(gap, dj * 1e-12f));                                \
  float m0[4] = {-1e30f, -1e30f, -1e30f, -1e30f};                                      \
  float m1[4] = {-1e30f, -1e30f, -1e30f, -1e30f};                                      \
  _Pragma("unroll")                                                                    \
  for (int p = 0; p < 16; ++p) {                                                       \
    float dr = xhr - PRT[p], di = xhi - PIT[p];                                        \
    float met = -(dr * dr + di * di) * inoe;                                           \
    _Pragma("unroll")                                                                  \
    for (int k = 0; k < 4; ++k) {                                                      \
      if ((p >> (3 - k)) & 1) m1[k] = fmaxf(m1[k], met);                               \
      else                    m0[k] = fmaxf(m0[k], met);                               \
    }                                                                                  \
  }                                                                                    \
  _Pragma("unroll")                                                                    \
  for (int k = 0; k < 4; ++k) Lout[k] = m0[k] - m1[k];                                 \
}

// ---------------- fused LMMSE + BP, one block per (bt, plane) --------------
// Phase 1: threads 0..249 each run the full per-symbol chain (channel,
// Gram, rsqrt-Cholesky, y-solve) and the per-column solve+demap for THIS
// plane's 2 UE columns only; LLRs staged in LDS (sL).  The shared chain is
// duplicated across the 2 planes (cheap: its full-rate VALU demand is
// small) in exchange for killing the Lch3 global round-trip, one kernel
// launch, and -- the big one -- overlapping the latency-bound solve chains
// with other blocks' VALU-dense BP phases instead of running them on an
// idle machine.
// Phase 2: identical LDS-resident BP (2 codewords = this plane).
__global__ void __launch_bounds__(256, 4)
k_fused(const float* __restrict__ h_re, const float* __restrict__ h_im,
        const float* __restrict__ n_re, const float* __restrict__ n_im,
        const double* __restrict__ nobuf,
        const unsigned* __restrict__ bpack, const unsigned* __restrict__ Ppack,
        const int* __restrict__ vlist, const int* __restrict__ coff,
        const int* __restrict__ cinfo, float* __restrict__ out, int ncw) {
  __shared__ float2 sT[EMAX];    // tanh(v2c/2) per info-edge slot (16 KB)
  __shared__ float2 sP[512];     // per-check product of tanh (4 KB)
  __shared__ float2 sL[NNODES];  // staged LLRs for this plane (8 KB)

  int tid = threadIdx.x;
  int pairId = blockIdx.x;       // = bt*2 + plane
  int bt = pairId >> 1, plane = pairId & 1;

  // ================= phase 1: LMMSE for this block's 250 symbols ===========
  if (tid < NSYM) {
    int t = bt * NSYM + tid;
    int s = tid;

    float no = (float)nobuf[0];
    float sq = (float)nobuf[1];
    const float is2 = 0.70710678118654752f;  // 1/sqrt(2)

    float Hr[4][4], Hi[4][4];
    {
      const float4* hr4 = (const float4*)h_re;
      const float4* hi4 = (const float4*)h_im;
      #pragma unroll
      for (int i = 0; i < 4; ++i) {
        float4 a = hr4[t * 4 + i], c = hi4[t * 4 + i];
        Hr[i][0] = a.x * is2; Hr[i][1] = a.y * is2;
        Hr[i][2] = a.z * is2; Hr[i][3] = a.w * is2;
        Hi[i][0] = c.x * is2; Hi[i][1] = c.y * is2;
        Hi[i][2] = c.z * is2; Hi[i][3] = c.w * is2;
      }
    }

    // transmitted symbols: encode+map inline
    float xr[4], xi[4];
    #pragma unroll
    for (int ue = 0; ue < 4; ++ue) {
      const unsigned* bp = bpack + (bt * 4 + ue) * 16;
      int v = 0;
      #pragma unroll
      for (int k = 0; k < 4; ++k) {
        int n = 4 * s + k;
        int bit;
        if (n < KK) {
          bit = (bp[n >> 5] >> (n & 31)) & 1;
        } else {
          const unsigned* pp = Ppack + (n - KK) * 16;
          int cnt = 0;
          #pragma unroll
          for (int w = 0; w < 16; ++w) cnt += __popc(bp[w] & pp[w]);
          bit = cnt & 1;
        }
        v = (v << 1) | bit;  // MSB-first: weights 8,4,2,1
      }
      qam_pointf(v, xr[ue], xi[ue]);
    }

    // y = H x + w
    float yr[4], yi[4];
    {
      float4 wr = ((const float4*)n_re)[t];
      float4 wi = ((const float4*)n_im)[t];
      float wrv[4] = {wr.x, wr.y, wr.z, wr.w};
      float wiv[4] = {wi.x, wi.y, wi.z, wi.w};
      #pragma unroll
      for (int i = 0; i < 4; ++i) {
        float ar = wrv[i] * sq;
        float ai = wiv[i] * sq;
        #pragma unroll
        for (int j = 0; j < 4; ++j) {
          ar += Hr[i][j] * xr[j] - Hi[i][j] * xi[j];
          ai += Hr[i][j] * xi[j] + Hi[i][j] * xr[j];
        }
        yr[i] = ar; yi[i] = ai;
      }
    }

    // A = H H^H + no I, lower triangle, into scalars
    auto dotc = [&](int i, int j, float& ar, float& ai) {
      float r = 0.0f, m = 0.0f;
      #pragma unroll
      for (int k = 0; k < 4; ++k) {
        r += Hr[i][k] * Hr[j][k] + Hi[i][k] * Hi[j][k];
        m += Hi[i][k] * Hr[j][k] - Hr[i][k] * Hi[j][k];
      }
      ar = r; ai = m;
    };
    float a00, a11, a22, a33, dum;
    float a10r, a10i, a20r, a20i, a21r, a21i, a30r, a30i, a31r, a31i, a32r, a32i;
    dotc(0, 0, a00, dum);  a00 += no;
    dotc(1, 0, a10r, a10i);
    dotc(1, 1, a11, dum);  a11 += no;
    dotc(2, 0, a20r, a20i);
    dotc(2, 1, a21r, a21i);
    dotc(2, 2, a22, dum);  a22 += no;
    dotc(3, 0, a30r, a30i);
    dotc(3, 1, a31r, a31i);
    dotc(3, 2, a32r, a32i);
    dotc(3, 3, a33, dum);  a33 += no;

    // Cholesky in inverse-diagonal form
    float i00 = rsqrtf(a00);
    float L10r = a10r * i00, L10i = a10i * i00;
    float L20r = a20r * i00, L20i = a20i * i00;
    float L30r = a30r * i00, L30i = a30i * i00;
    float d11 = a11 - (L10r * L10r + L10i * L10i);
    float i11 = rsqrtf(d11);
    float L21r = (a21r - (L20r * L10r + L20i * L10i)) * i11;
    float L21i = (a21i - (L20i * L10r - L20r * L10i)) * i11;
    float L31r = (a31r - (L30r * L10r + L30i * L10i)) * i11;
    float L31i = (a31i - (L30i * L10r - L30r * L10i)) * i11;
    float d22 = a22 - (L20r * L20r + L20i * L20i) - (L21r * L21r + L21i * L21i);
    float i22 = rsqrtf(d22);
    float L32r = (a32r - (L30r * L20r + L30i * L20i) - (L31r * L21r + L31i * L21i)) * i22;
    float L32i = (a32i - (L30i * L20r - L30r * L20i) - (L31i * L21r - L31r * L21i)) * i22;
    float d33 = a33 - (L30r * L30r + L30i * L30i) - (L31r * L31r + L31i * L31i)
                    - (L32r * L32r + L32i * L32i);
    float i33 = rsqrtf(d33);

    // forward solve on y only: v = L^{-1} y (in place)
    {
      float v0r = yr[0] * i00,               v0i = yi[0] * i00;
      float v1r = (yr[1] - (L10r * v0r - L10i * v0i)) * i11;
      float v1i = (yi[1] - (L10r * v0i + L10i * v0r)) * i11;
      float v2r = (yr[2] - (L20r * v0r - L20i * v0i) - (L21r * v1r - L21i * v1i)) * i22;
      float v2i = (yi[2] - (L20r * v0i + L20i * v0r) - (L21r * v1i + L21i * v1r)) * i22;
      float v3r = (yr[3] - (L30r * v0r - L30i * v0i) - (L31r * v1r - L31i * v1i)
                         - (L32r * v2r - L32i * v2i)) * i33;
      float v3i = (yi[3] - (L30r * v0i + L30i * v0r) - (L31r * v1i + L31i * v1r)
                         - (L32r * v2i + L32i * v2r)) * i33;
      yr[0] = v0r; yi[0] = v0i; yr[1] = v1r; yi[1] = v1i;
      yr[2] = v2r; yi[2] = v2i; yr[3] = v3r; yi[3] = v3i;
    }

    // fp32 16-QAM table
    const float PRT[16] = { 0.31622776601683794f, 0.31622776601683794f, 0.9486832980505138f, 0.9486832980505138f,
                            0.31622776601683794f, 0.31622776601683794f, 0.9486832980505138f, 0.9486832980505138f,
                           -0.31622776601683794f,-0.31622776601683794f,-0.9486832980505138f,-0.9486832980505138f,
                           -0.31622776601683794f,-0.31622776601683794f,-0.9486832980505138f,-0.9486832980505138f };
    const float PIT[16] = { 0.31622776601683794f, 0.9486832980505138f, 0.31622776601683794f, 0.9486832980505138f,
                           -0.31622776601683794f,-0.9486832980505138f,-0.31622776601683794f,-0.9486832980505138f,
                            0.31622776601683794f, 0.9486832980505138f, 0.31622776601683794f, 0.9486832980505138f,
                           -0.31622776601683794f,-0.9486832980505138f,-0.31622776601683794f,-0.9486832980505138f };

    // only this plane's 2 UE columns (uniform branch per block)
    float lA[4], lB[4];
    if (plane == 0) {
      SOLVE_DEMAP(0, lA);
      SOLVE_DEMAP(1, lB);
    } else {
      SOLVE_DEMAP(2, lA);
      SOLVE_DEMAP(3, lB);
    }
    #pragma unroll
    for (int k = 0; k < 4; ++k) {
      sL[4 * s + k] = make_float2(lA[k], lB[k]);
    }
  }
  __syncthreads();

  // ================= phase 2: LDS-resident BP (2 codewords) ===============
  // own info-node state in registers
  float2 Ln[2], En[2];
  int pk0[2], pk1[2], pk2[2]; bool iok[2];
  #pragma unroll
  for (int i = 0; i < 2; ++i) {
    int n = tid + TB * i;
    iok[i] = n < KK;
    Ln[i] = make_float2(0.f, 0.f);
    En[i] = make_float2(1.f, 1.f);
    pk0[i] = pk1[i] = pk2[i] = 0;
    if (iok[i]) {
      float2 L = sL[n];
      Ln[i] = L;
      En[i] = make_float2(__expf(fminf(fmaxf(L.x, -55.f), 55.f)),
                          __expf(fminf(fmaxf(L.y, -55.f), 55.f)));
      int s0 = vlist[n * MAXVDEG], s1 = vlist[n * MAXVDEG + 1], s2 = vlist[n * MAXVDEG + 2];
      pk0[i] = (cinfo[s0] & 0xffff0000) | s0;
      pk1[i] = (cinfo[s1] & 0xffff0000) | s1;
      pk2[i] = (cinfo[s2] & 0xffff0000) | s2;
    }
  }
  // per-check constant: tanh of the parity-node LLR (check c <-> parity var KK+c)
  float2 qpar0, qpar1;
  {
    float2 Lp0 = sL[KK + tid];
    qpar0 = make_float2(tanh_half(Lp0.x), tanh_half(Lp0.y));
  }
  bool c1ok = (tid + TB) < MM;
  if (c1ok) {
    float2 Lp1 = sL[KK + tid + TB];
    qpar1 = make_float2(tanh_half(Lp1.x), tanh_half(Lp1.y));
  } else {
    qpar1 = make_float2(1.f, 1.f);
  }
  int beg0 = coff[tid], end0 = coff[tid + 1];
  int beg1 = c1ok ? coff[tid + TB] : 0;
  int end1 = c1ok ? coff[tid + TB + 1] : 0;

  for (int it = 0; it < NITERS; ++it) {
    // ---- pass 1: info-node var update ----
    if (it == 0) {
      #pragma unroll
      for (int i = 0; i < 2; ++i) {
        if (iok[i]) {
          float2 t = make_float2(tanh_half(Ln[i].x), tanh_half(Ln[i].y));
          sT[pk0[i] & 0xffff] = t;
          sT[pk1[i] & 0xffff] = t;
          sT[pk2[i] & 0xffff] = t;
        }
      }
    } else {
      #pragma unroll
      for (int i = 0; i < 2; ++i) {
        if (iok[i]) {
          int s0 = pk0[i] & 0xffff, c0 = ((unsigned)pk0[i]) >> 16;
          int s1 = pk1[i] & 0xffff, c1 = ((unsigned)pk1[i]) >> 16;
          int s2 = pk2[i] & 0xffff, c2 = ((unsigned)pk2[i]) >> 16;
          float2 P0 = sP[c0], P1 = sP[c1], P2 = sP[c2];
          float2 t0 = sT[s0], t1 = sT[s1], t2 = sT[s2];
          // lane x
          float p0 = pclip(P0.x, t0.x), p1 = pclip(P1.x, t1.x), p2 = pclip(P2.x, t2.x);
          float a0 = t0.x + p0, a1 = t1.x + p1, a2 = t2.x + p2;
          float b0 = t0.x - p0, b1 = t1.x - p1, b2 = t2.x - p2;
          float Ex = En[i].x;
          float A0 = Ex * (a1 * a2), A1 = Ex * (a0 * a2), A2 = Ex * (a0 * a1);
          float B0 = b1 * b2,        B1 = b0 * b2,        B2 = b0 * b1;
          float n0x = tfloor(__fdividef(A0 - B0, A0 + B0));
          float n1x = tfloor(__fdividef(A1 - B1, A1 + B1));
          float n2x = tfloor(__fdividef(A2 - B2, A2 + B2));
          // lane y
          float q0 = pclip(P0.y, t0.y), q1 = pclip(P1.y, t1.y), q2 = pclip(P2.y, t2.y);
          float c0a = t0.y + q0, c1a = t1.y + q1, c2a = t2.y + q2;
          float d0b = t0.y - q0, d1b = t1.y - q1, d2b = t2.y - q2;
          float Ey = En[i].y;
          float C0 = Ey * (c1a * c2a), C1 = Ey * (c0a * c2a), C2 = Ey * (c0a * c1a);
          float D0 = d1b * d2b,        D1 = d0b * d2b,        D2 = d0b * d1b;
          float n0y = tfloor(__fdividef(C0 - D0, C0 + D0));
          float n1y = tfloor(__fdividef(C1 - D1, C1 + D1));
          float n2y = tfloor(__fdividef(C2 - D2, C2 + D2));
          sT[s0] = make_float2(n0x, n0y);
          sT[s1] = make_float2(n1x, n1y);
          sT[s2] = make_float2(n2x, n2y);
        }
      }
    }
    __syncthreads();
    // ---- pass 2: per-check products (parity factor from register) ----
    {
      float px = qpar0.x, py = qpar0.y;
      for (int e = beg0; e < end0 - 1; ++e) { float2 tt = sT[e]; px *= tt.x; py *= tt.y; }
      sP[tid] = make_float2(px, py);
      if (c1ok) {
        float qx = qpar1.x, qy = qpar1.y;
        for (int e = beg1; e < end1 - 1; ++e) { float2 tt = sT[e]; qx *= tt.x; qy *= tt.y; }
        sP[tid + TB] = make_float2(qx, qy);
      }
    }
    __syncthreads();
  }

  // ---- decide: additive log form (once) ----
  int cw0 = pairId * 2;
  float* o0 = out + (size_t)ncw * KK + (size_t)cw0 * KK;
  float* o1 = o0 + KK;
  #pragma unroll
  for (int i = 0; i < 2; ++i) {
    if (iok[i]) {
      int n = tid + TB * i;
      int s0 = pk0[i] & 0xffff, c0 = ((unsigned)pk0[i]) >> 16;
      int s1 = pk1[i] & 0xffff, c1 = ((unsigned)pk1[i]) >> 16;
      int s2 = pk2[i] & 0xffff, c2 = ((unsigned)pk2[i]) >> 16;
      float2 P0 = sP[c0], P1 = sP[c1], P2 = sP[c2];
      float2 t0 = sT[s0], t1 = sT[s1], t2 = sT[s2];
      float2 L = Ln[i];
      float ax = L.x + atanh2c(P0.x, t0.x) + atanh2c(P1.x, t1.x) + atanh2c(P2.x, t2.x);
      float ay = L.y + atanh2c(P0.y, t0.y) + atanh2c(P1.y, t1.y) + atanh2c(P2.y, t2.y);
      o0[n] = (ax < 0.0f) ? 1.0f : 0.0f;
      o1[n] = (ay < 0.0f) ? 1.0f : 0.0f;
    }
  }
}

// ---------------- launcher ----------------
extern "C" void kernel_launch(void* const* d_in, const int* in_sizes, int n_in,
                              void* d_out, int out_size, void* d_ws, size_t ws_size,
                              hipStream_t stream) {
  const float* ebno = (const float*)d_in[1];
  const int*   b    = (const int*)d_in[2];
  const int*   P    = (const int*)d_in[3];
  const int*   cn   = (const int*)d_in[4];
  const int*   vn   = (const int*)d_in[5];
  const float* h_re = (const float*)d_in[6];
  const float* h_im = (const float*)d_in[7];
  const float* nre  = (const float*)d_in[8];
  const float* nim  = (const float*)d_in[9];
  float* out = (float*)d_out;

  int E     = in_sizes[4];
  int batch = in_sizes[2] / (4 * KK);
  int ncw   = batch * 4;

  char* ws = (char*)d_ws;
  size_t off = 0;
  auto alloc = [&](size_t bytes) -> void* {
    void* p = ws + off;
    off += (bytes + 255) & ~(size_t)255;
    return p;
  };
  unsigned* Ppack  = (unsigned*)alloc((size_t)MM * 16 * 4);
  unsigned* bpack  = (unsigned*)alloc((size_t)ncw * 16 * 4);
  int*      coff   = (int*)alloc((size_t)(MM + 1) * 4);
  int*      cinfo  = (int*)alloc((size_t)EMAX * 4);
  int*      vlist  = (int*)alloc((size_t)NNODES * MAXVDEG * 4);
  double*   nobuf  = (double*)alloc(2 * 8);
  (void)ws_size; (void)n_in; (void)out_size;

  int packItems  = MM * 16 + ncw * 16;
  int packBlocks = (packItems + 511) / 512;
  int bfBlocks   = (ncw * KK + 511) / 512;
  int setupGrid  = 1 + packBlocks + bfBlocks;

  k_setup<<<dim3(setupGrid), dim3(512), 0, stream>>>(cn, vn, E, ebno, P, b, ncw,
                                                     cinfo, vlist, coff, nobuf,
                                                     Ppack, bpack, out, packBlocks);
  k_fused<<<dim3(ncw / 2), dim3(256), 0, stream>>>(h_re, h_im, nre, nim, nobuf,
                                                   bpack, Ppack, vlist, coff, cinfo,
                                                   out, ncw);
}

// Round 3
// 178.569 us; speedup vs baseline: 1.0323x; 1.0002x over previous
//
#include <hip/hip_runtime.h>
#include <math.h>

// Problem constants (from reference)
#define KK     500   // info bits
#define MM     500   // parity checks
#define NNODES 1000  // N = K + M variable nodes
#define NSYM   250   // N / BPS
#define NITERS 5
#define MAXVDEG 4    // info vars degree exactly 3 (row weight of P), parity vars 1
#define EMAX   2560  // padded slots: E + M = 2500 max
#define TB     256

// ---------------- setup: graph build + bit packing + bf output -------------
// Round-14 layout: checks are COUNTING-SORTED by total degree and relabeled
// (new id = rank).  Each check's slot range is padded to ODD length so that
// within a wave (uniform degree after sorting) the lane stride in sT is an
// odd number of float2 -> lanes spread over 16 banks (~4-way, near-free)
// instead of 4 banks (~16-way).  Info edges fill [beg, beg+d-1), parity edge
// pinned at beg+d-1, pad slot (if any) unused.
__global__ void __launch_bounds__(512)
k_setup(const int* __restrict__ cn, const int* __restrict__ vn, int E,
        const float* __restrict__ ebno, const int* __restrict__ P,
        const int* __restrict__ b, int ncw,
        int* __restrict__ cinfo, int* __restrict__ vlist, int* __restrict__ coff,
        int* __restrict__ cdend, int* __restrict__ cperm,
        double* __restrict__ nobuf, unsigned* __restrict__ Ppack,
        unsigned* __restrict__ bpack, float* __restrict__ out, int packBlocks) {
  __shared__ int sdeg[512];   // orig check -> total degree
  __shared__ int scinv[512];  // orig check -> new id
  __shared__ int srlen[512];  // new id -> padded (odd) range length
  __shared__ int sdnew[512];  // new id -> degree
  __shared__ int sexcl[512];  // new id -> range begin
  __shared__ int ssc[512];
  __shared__ int scur[512];
  __shared__ int svc[NNODES];
  __shared__ int shist[64];
  __shared__ int shcur[64];
  int tid = threadIdx.x;
  int bx = blockIdx.x;

  if (bx == 0) {
    sdeg[tid] = 0;
    for (int n = tid; n < NNODES; n += 512) svc[n] = 0;
    if (tid < 64) { shist[tid] = 0; shcur[tid] = 0; }
    __syncthreads();
    for (int e = tid; e < E; e += 512) atomicAdd(&sdeg[cn[e]], 1);
    __syncthreads();
    int d = (tid < MM) ? sdeg[tid] : 0;
    if (tid < MM) atomicAdd(&shist[d], 1);
    __syncthreads();
    if (tid == 0) {
      int acc = 0;
      for (int i = 0; i < 64; ++i) { int h = shist[i]; shist[i] = acc; shcur[i] = acc; acc += h; }
    }
    __syncthreads();
    if (tid < MM) {
      int nid = atomicAdd(&shcur[d], 1);
      scinv[tid] = nid;
      cperm[nid] = tid;          // new -> orig (for parity-LLR lookup)
      sdnew[nid] = d;
      srlen[nid] = d + ((d & 1) ^ 1);   // pad to odd
    }
    __syncthreads();
    // scan padded lengths over NEW order
    int v = (tid < MM) ? srlen[tid] : 0;
    ssc[tid] = v;
    __syncthreads();
    for (int o = 1; o < 512; o <<= 1) {
      int x = (tid >= o) ? ssc[tid - o] : 0;
      __syncthreads();
      ssc[tid] += x;
      __syncthreads();
    }
    int excl = ssc[tid] - v;
    sexcl[tid] = excl;
    scur[tid] = excl;
    if (tid < MM) {
      coff[tid]  = excl;
      cdend[tid] = excl + sdnew[tid] - 1;  // product loop: [beg, dend) = info edges
      if (tid == MM - 1) coff[MM] = ssc[tid];
    }
    __syncthreads();
    for (int e = tid; e < E; e += 512) {
      int c = cn[e], n = vn[e];
      int nc = scinv[c];
      int slot;
      if (n >= KK) {
        slot = sexcl[nc] + sdeg[c] - 1;    // parity edge -> last used slot
      } else {
        slot = atomicAdd(&scur[nc], 1);    // info edges fill [beg, beg+d-1)
      }
      cinfo[slot] = (nc << 16) | n;
      if (n < KK) {
        int t = atomicAdd(&svc[n], 1);
        if (t < MAXVDEG) vlist[n * MAXVDEG + t] = slot;
      }
    }
    if (tid == 0) {
      double no = 1.0 / (pow(10.0, (double)ebno[0] * 0.1) * 2.0);  // BPS*RATE = 2
      nobuf[0] = no;
      nobuf[1] = sqrt(no * 0.5);
    }
    return;
  }

  if (bx <= packBlocks) {
    int id = (bx - 1) * 512 + tid;
    if (id < MM * 16) {
      int j = id >> 4, w = id & 15;
      unsigned word = 0u;
      int base = w * 32;
      for (int bit = 0; bit < 32; ++bit) {
        int i = base + bit;
        if (i < KK && P[i * MM + j] != 0) word |= (1u << bit);
      }
      Ppack[j * 16 + w] = word;
    } else {
      int id2 = id - MM * 16;
      if (id2 < ncw * 16) {
        int cw = id2 >> 4, w = id2 & 15;
        unsigned word = 0u;
        int base = w * 32;
        for (int bit = 0; bit < 32; ++bit) {
          int i = base + bit;
          if (i < KK && b[cw * KK + i] != 0) word |= (1u << bit);
        }
        bpack[cw * 16 + w] = word;
      }
    }
    return;
  }

  int id = (bx - 1 - packBlocks) * 512 + tid;
  if (id < ncw * KK) out[id] = (float)b[id];
}

// ---------------- 16-QAM constellation (fp32 TX symbol) --------------------
__device__ __forceinline__ void qam_pointf(int p, float& re, float& im) {
  const float s = 0.31622776601683794f;  // 1/sqrt(10)
  int b0 = (p >> 3) & 1, b1 = (p >> 2) & 1, b2 = (p >> 1) & 1, b3 = p & 1;
  re = (float)((1 - 2 * b0) * (2 - (1 - 2 * b2))) * s;
  im = (float)((1 - 2 * b1) * (2 - (1 - 2 * b3))) * s;
}

// ---------------- BP helpers ----------------
__device__ __forceinline__ float tanh_half(float m) {
  float mc = fminf(fmaxf(m, -19.8f), 19.8f);
  float e = __expf(mc);
  float t = 1.0f - __fdividef(2.0f, e + 1.0f);
  return (t >= 0.0f) ? fmaxf(t, 1e-7f) : fminf(t, -1e-7f);
}
__device__ __forceinline__ float pclip(float P, float t) {
  return copysignf(fminf(fabsf(P), 0.999999f * fabsf(t)), P);
}
__device__ __forceinline__ float tfloor(float t) {
  return (t >= 0.0f) ? fmaxf(t, 1e-7f) : fminf(t, -1e-7f);
}
__device__ __forceinline__ float atanh2c(float P, float t) {
  float r = __fdividef(P, t);
  r = fminf(fmaxf(r, -0.999999f), 0.999999f);
  return __logf(__fdividef(1.0f + r, 1.0f - r));
}

// per-column forward solve + max-log demap, column index J compile-time.
#define SOLVE_DEMAP(J, Lout) {                                                          \
  float u0r = Hr[0][J] * i00,               u0i = Hi[0][J] * i00;                       \
  float u1r = (Hr[1][J] - (L10r * u0r - L10i * u0i)) * i11;                             \
  float u1i = (Hi[1][J] - (L10r * u0i + L10i * u0r)) * i11;                             \
  float u2r = (Hr[2][J] - (L20r * u0r - L20i * u0i) - (L21r * u1r - L21i * u1i)) * i22; \
  float u2i = (Hi[2][J] - (L20r * u0i + L20i * u0r) - (L21r * u1i + L21i * u1r)) * i22; \
  float u3r = (Hr[3][J] - (L30r * u0r - L30i * u0i) - (L31r * u1r - L31i * u1i)         \
                        - (L32r * u2r - L32i * u2i)) * i33;                             \
  float u3i = (Hi[3][J] - (L30r * u0i + L30i * u0r) - (L31r * u1i + L31i * u1r)         \
                        - (L32r * u2i + L32i * u2r)) * i33;                             \
  float dj = (u0r * u0r + u0i * u0i) + (u1r * u1r + u1i * u1i)                          \
           + (u2r * u2r + u2i * u2i) + (u3r * u3r + u3i * u3i);                         \
  float rr = (u0r * yr[0] + u0i * yi[0]) + (u1r * yr[1] + u1i * yi[1])                  \
           + (u2r * yr[2] + u2i * yi[2]) + (u3r * yr[3] + u3i * yi[3]);                 \
  float ri = (u0r * yi[0] - u0i * yr[0]) + (u1r * yi[1] - u1i * yr[1])                  \
           + (u2r * yi[2] - u2i * yr[2]) + (u3r * yi[3] - u3i * yr[3]);                 \
  float rdj = __fdividef(1.0f, dj);                                                    \
  float xhr = rr * rdj, xhi = ri * rdj;                                                \
  float gap = 1.0f - dj;                                                               \
  float inoe = __fdividef(dj, fmaxf(gap, dj * 1e-12f));                                \
  float m0[4] = {-1e30f, -1e30f, -1e30f, -1e30f};                                      \
  float m1[4] = {-1e30f, -1e30f, -1e30f, -1e30f};                                      \
  _Pragma("unroll")                                                                    \
  for (int p = 0; p < 16; ++p) {                                                       \
    float dr = xhr - PRT[p], di = xhi - PIT[p];                                        \
    float met = -(dr * dr + di * di) * inoe;                                           \
    _Pragma("unroll")                                                                  \
    for (int k = 0; k < 4; ++k) {                                                      \
      if ((p >> (3 - k)) & 1) m1[k] = fmaxf(m1[k], met);                               \
      else                    m0[k] = fmaxf(m0[k], met);                               \
    }                                                                                  \
  }                                                                                    \
  _Pragma("unroll")                                                                    \
  for (int k = 0; k < 4; ++k) Lout[k] = m0[k] - m1[k];                                 \
}

// ---------------- fused LMMSE + BP, one block per (bt, plane) --------------
// sL aliases sT[0..NNODES): the staged LLRs are dead after BP-init reads
// (Ln/En/qpar), and sT is first written after the post-init barrier.
// LDS total = 20.5 + 4 KB = 24.5 KB -> 6 blocks/CU (was 5 at 28.6 KB).
__global__ void __launch_bounds__(256, 4)
k_fused(const float* __restrict__ h_re, const float* __restrict__ h_im,
        const float* __restrict__ n_re, const float* __restrict__ n_im,
        const double* __restrict__ nobuf,
        const unsigned* __restrict__ bpack, const unsigned* __restrict__ Ppack,
        const int* __restrict__ vlist, const int* __restrict__ coff,
        const int* __restrict__ cdend, const int* __restrict__ cperm,
        const int* __restrict__ cinfo, float* __restrict__ out, int ncw) {
  __shared__ float2 sT[EMAX];    // tanh(v2c/2) per info-edge slot (20.5 KB)
  __shared__ float2 sP[512];     // per-check product of tanh (4 KB)
  float2* sL = sT;               // staged LLRs alias (first NNODES entries)

  int tid = threadIdx.x;
  int pairId = blockIdx.x;       // = bt*2 + plane
  int bt = pairId >> 1, plane = pairId & 1;

  // ================= phase 1: LMMSE for this block's 250 symbols ===========
  if (tid < NSYM) {
    int t = bt * NSYM + tid;
    int s = tid;

    float no = (float)nobuf[0];
    float sq = (float)nobuf[1];
    const float is2 = 0.70710678118654752f;  // 1/sqrt(2)

    float Hr[4][4], Hi[4][4];
    {
      const float4* hr4 = (const float4*)h_re;
      const float4* hi4 = (const float4*)h_im;
      #pragma unroll
      for (int i = 0; i < 4; ++i) {
        float4 a = hr4[t * 4 + i], c = hi4[t * 4 + i];
        Hr[i][0] = a.x * is2; Hr[i][1] = a.y * is2;
        Hr[i][2] = a.z * is2; Hr[i][3] = a.w * is2;
        Hi[i][0] = c.x * is2; Hi[i][1] = c.y * is2;
        Hi[i][2] = c.z * is2; Hi[i][3] = c.w * is2;
      }
    }

    // transmitted symbols: encode+map inline
    float xr[4], xi[4];
    #pragma unroll
    for (int ue = 0; ue < 4; ++ue) {
      const unsigned* bp = bpack + (bt * 4 + ue) * 16;
      int v = 0;
      #pragma unroll
      for (int k = 0; k < 4; ++k) {
        int n = 4 * s + k;
        int bit;
        if (n < KK) {
          bit = (bp[n >> 5] >> (n & 31)) & 1;
        } else {
          const unsigned* pp = Ppack + (n - KK) * 16;
          int cnt = 0;
          #pragma unroll
          for (int w = 0; w < 16; ++w) cnt += __popc(bp[w] & pp[w]);
          bit = cnt & 1;
        }
        v = (v << 1) | bit;  // MSB-first: weights 8,4,2,1
      }
      qam_pointf(v, xr[ue], xi[ue]);
    }

    // y = H x + w
    float yr[4], yi[4];
    {
      float4 wr = ((const float4*)n_re)[t];
      float4 wi = ((const float4*)n_im)[t];
      float wrv[4] = {wr.x, wr.y, wr.z, wr.w};
      float wiv[4] = {wi.x, wi.y, wi.z, wi.w};
      #pragma unroll
      for (int i = 0; i < 4; ++i) {
        float ar = wrv[i] * sq;
        float ai = wiv[i] * sq;
        #pragma unroll
        for (int j = 0; j < 4; ++j) {
          ar += Hr[i][j] * xr[j] - Hi[i][j] * xi[j];
          ai += Hr[i][j] * xi[j] + Hi[i][j] * xr[j];
        }
        yr[i] = ar; yi[i] = ai;
      }
    }

    // A = H H^H + no I, lower triangle, into scalars
    auto dotc = [&](int i, int j, float& ar, float& ai) {
      float r = 0.0f, m = 0.0f;
      #pragma unroll
      for (int k = 0; k < 4; ++k) {
        r += Hr[i][k] * Hr[j][k] + Hi[i][k] * Hi[j][k];
        m += Hi[i][k] * Hr[j][k] - Hr[i][k] * Hi[j][k];
      }
      ar = r; ai = m;
    };
    float a00, a11, a22, a33, dum;
    float a10r, a10i, a20r, a20i, a21r, a21i, a30r, a30i, a31r, a31i, a32r, a32i;
    dotc(0, 0, a00, dum);  a00 += no;
    dotc(1, 0, a10r, a10i);
    dotc(1, 1, a11, dum);  a11 += no;
    dotc(2, 0, a20r, a20i);
    dotc(2, 1, a21r, a21i);
    dotc(2, 2, a22, dum);  a22 += no;
    dotc(3, 0, a30r, a30i);
    dotc(3, 1, a31r, a31i);
    dotc(3, 2, a32r, a32i);
    dotc(3, 3, a33, dum);  a33 += no;

    // Cholesky in inverse-diagonal form
    float i00 = rsqrtf(a00);
    float L10r = a10r * i00, L10i = a10i * i00;
    float L20r = a20r * i00, L20i = a20i * i00;
    float L30r = a30r * i00, L30i = a30i * i00;
    float d11 = a11 - (L10r * L10r + L10i * L10i);
    float i11 = rsqrtf(d11);
    float L21r = (a21r - (L20r * L10r + L20i * L10i)) * i11;
    float L21i = (a21i - (L20i * L10r - L20r * L10i)) * i11;
    float L31r = (a31r - (L30r * L10r + L30i * L10i)) * i11;
    float L31i = (a31i - (L30i * L10r - L30r * L10i)) * i11;
    float d22 = a22 - (L20r * L20r + L20i * L20i) - (L21r * L21r + L21i * L21i);
    float i22 = rsqrtf(d22);
    float L32r = (a32r - (L30r * L20r + L30i * L20i) - (L31r * L21r + L31i * L21i)) * i22;
    float L32i = (a32i - (L30i * L20r - L30r * L20i) - (L31i * L21r - L31r * L21i)) * i22;
    float d33 = a33 - (L30r * L30r + L30i * L30i) - (L31r * L31r + L31i * L31i)
                    - (L32r * L32r + L32i * L32i);
    float i33 = rsqrtf(d33);

    // forward solve on y only: v = L^{-1} y (in place)
    {
      float v0r = yr[0] * i00,               v0i = yi[0] * i00;
      float v1r = (yr[1] - (L10r * v0r - L10i * v0i)) * i11;
      float v1i = (yi[1] - (L10r * v0i + L10i * v0r)) * i11;
      float v2r = (yr[2] - (L20r * v0r - L20i * v0i) - (L21r * v1r - L21i * v1i)) * i22;
      float v2i = (yi[2] - (L20r * v0i + L20i * v0r) - (L21r * v1i + L21i * v1r)) * i22;
      float v3r = (yr[3] - (L30r * v0r - L30i * v0i) - (L31r * v1r - L31i * v1i)
                         - (L32r * v2r - L32i * v2i)) * i33;
      float v3i = (yi[3] - (L30r * v0i + L30i * v0r) - (L31r * v1i + L31i * v1r)
                         - (L32r * v2i + L32i * v2r)) * i33;
      yr[0] = v0r; yi[0] = v0i; yr[1] = v1r; yi[1] = v1i;
      yr[2] = v2r; yi[2] = v2i; yr[3] = v3r; yi[3] = v3i;
    }

    // fp32 16-QAM table
    const float PRT[16] = { 0.31622776601683794f, 0.31622776601683794f, 0.9486832980505138f, 0.9486832980505138f,
                            0.31622776601683794f, 0.31622776601683794f, 0.9486832980505138f, 0.9486832980505138f,
                           -0.31622776601683794f,-0.31622776601683794f,-0.9486832980505138f,-0.9486832980505138f,
                           -0.31622776601683794f,-0.31622776601683794f,-0.9486832980505138f,-0.9486832980505138f };
    const float PIT[16] = { 0.31622776601683794f, 0.9486832980505138f, 0.31622776601683794f, 0.9486832980505138f,
                           -0.31622776601683794f,-0.9486832980505138f,-0.31622776601683794f,-0.9486832980505138f,
                            0.31622776601683794f, 0.9486832980505138f, 0.31622776601683794f, 0.9486832980505138f,
                           -0.31622776601683794f,-0.9486832980505138f,-0.31622776601683794f,-0.9486832980505138f };

    // only this plane's 2 UE columns (uniform branch per block)
    float lA[4], lB[4];
    if (plane == 0) {
      SOLVE_DEMAP(0, lA);
      SOLVE_DEMAP(1, lB);
    } else {
      SOLVE_DEMAP(2, lA);
      SOLVE_DEMAP(3, lB);
    }
    #pragma unroll
    for (int k = 0; k < 4; ++k) {
      sL[4 * s + k] = make_float2(lA[k], lB[k]);
    }
  }
  __syncthreads();

  // ================= phase 2: LDS-resident BP (2 codewords) ===============
  // own info-node state in registers
  float2 Ln[2], En[2];
  int pk0[2], pk1[2], pk2[2]; bool iok[2];
  #pragma unroll
  for (int i = 0; i < 2; ++i) {
    int n = tid + TB * i;
    iok[i] = n < KK;
    Ln[i] = make_float2(0.f, 0.f);
    En[i] = make_float2(1.f, 1.f);
    pk0[i] = pk1[i] = pk2[i] = 0;
    if (iok[i]) {
      float2 L = sL[n];
      Ln[i] = L;
      En[i] = make_float2(__expf(fminf(fmaxf(L.x, -55.f), 55.f)),
                          __expf(fminf(fmaxf(L.y, -55.f), 55.f)));
      int s0 = vlist[n * MAXVDEG], s1 = vlist[n * MAXVDEG + 1], s2 = vlist[n * MAXVDEG + 2];
      pk0[i] = (cinfo[s0] & 0xffff0000) | s0;
      pk1[i] = (cinfo[s1] & 0xffff0000) | s1;
      pk2[i] = (cinfo[s2] & 0xffff0000) | s2;
    }
  }
  // per-check constant: tanh of the parity-node LLR.  Check tid (new id)
  // corresponds to ORIGINAL check cperm[tid]; its parity var is KK+orig.
  float2 qpar0, qpar1;
  {
    int oc0 = cperm[tid];
    float2 Lp0 = sL[KK + oc0];
    qpar0 = make_float2(tanh_half(Lp0.x), tanh_half(Lp0.y));
  }
  bool c1ok = (tid + TB) < MM;
  if (c1ok) {
    int oc1 = cperm[tid + TB];
    float2 Lp1 = sL[KK + oc1];
    qpar1 = make_float2(tanh_half(Lp1.x), tanh_half(Lp1.y));
  } else {
    qpar1 = make_float2(1.f, 1.f);
  }
  int beg0 = coff[tid],                  dnd0 = cdend[tid];
  int beg1 = c1ok ? coff[tid + TB]  : 0, dnd1 = c1ok ? cdend[tid + TB] : 0;
  __syncthreads();  // sL (= sT[0..1000)) reads done; sT writes may now begin

  for (int it = 0; it < NITERS; ++it) {
    // ---- pass 1: info-node var update ----
    if (it == 0) {
      #pragma unroll
      for (int i = 0; i < 2; ++i) {
        if (iok[i]) {
          float2 t = make_float2(tanh_half(Ln[i].x), tanh_half(Ln[i].y));
          sT[pk0[i] & 0xffff] = t;
          sT[pk1[i] & 0xffff] = t;
          sT[pk2[i] & 0xffff] = t;
        }
      }
    } else {
      #pragma unroll
      for (int i = 0; i < 2; ++i) {
        if (iok[i]) {
          int s0 = pk0[i] & 0xffff, c0 = ((unsigned)pk0[i]) >> 16;
          int s1 = pk1[i] & 0xffff, c1 = ((unsigned)pk1[i]) >> 16;
          int s2 = pk2[i] & 0xffff, c2 = ((unsigned)pk2[i]) >> 16;
          float2 P0 = sP[c0], P1 = sP[c1], P2 = sP[c2];
          float2 t0 = sT[s0], t1 = sT[s1], t2 = sT[s2];
          // lane x
          float p0 = pclip(P0.x, t0.x), p1 = pclip(P1.x, t1.x), p2 = pclip(P2.x, t2.x);
          float a0 = t0.x + p0, a1 = t1.x + p1, a2 = t2.x + p2;
          float b0 = t0.x - p0, b1 = t1.x - p1, b2 = t2.x - p2;
          float Ex = En[i].x;
          float A0 = Ex * (a1 * a2), A1 = Ex * (a0 * a2), A2 = Ex * (a0 * a1);
          float B0 = b1 * b2,        B1 = b0 * b2,        B2 = b0 * b1;
          float n0x = tfloor(__fdividef(A0 - B0, A0 + B0));
          float n1x = tfloor(__fdividef(A1 - B1, A1 + B1));
          float n2x = tfloor(__fdividef(A2 - B2, A2 + B2));
          // lane y
          float q0 = pclip(P0.y, t0.y), q1 = pclip(P1.y, t1.y), q2 = pclip(P2.y, t2.y);
          float c0a = t0.y + q0, c1a = t1.y + q1, c2a = t2.y + q2;
          float d0b = t0.y - q0, d1b = t1.y - q1, d2b = t2.y - q2;
          float Ey = En[i].y;
          float C0 = Ey * (c1a * c2a), C1 = Ey * (c0a * c2a), C2 = Ey * (c0a * c1a);
          float D0 = d1b * d2b,        D1 = d0b * d2b,        D2 = d0b * d1b;
          float n0y = tfloor(__fdividef(C0 - D0, C0 + D0));
          float n1y = tfloor(__fdividef(C1 - D1, C1 + D1));
          float n2y = tfloor(__fdividef(C2 - D2, C2 + D2));
          sT[s0] = make_float2(n0x, n0y);
          sT[s1] = make_float2(n1x, n1y);
          sT[s2] = make_float2(n2x, n2y);
        }
      }
    }
    __syncthreads();
    // ---- pass 2: per-check products (parity factor from register) ----
    // Sorted checks: lanes in a wave have equal degree (no divergence) and
    // odd slot stride (no power-of-2 bank collapse).
    {
      float px = qpar0.x, py = qpar0.y;
      for (int e = beg0; e < dnd0; ++e) { float2 tt = sT[e]; px *= tt.x; py *= tt.y; }
      sP[tid] = make_float2(px, py);
      if (c1ok) {
        float qx = qpar1.x, qy = qpar1.y;
        for (int e = beg1; e < dnd1; ++e) { float2 tt = sT[e]; qx *= tt.x; qy *= tt.y; }
        sP[tid + TB] = make_float2(qx, qy);
      }
    }
    __syncthreads();
  }

  // ---- decide: additive log form (once) ----
  int cw0 = pairId * 2;
  float* o0 = out + (size_t)ncw * KK + (size_t)cw0 * KK;
  float* o1 = o0 + KK;
  #pragma unroll
  for (int i = 0; i < 2; ++i) {
    if (iok[i]) {
      int n = tid + TB * i;
      int s0 = pk0[i] & 0xffff, c0 = ((unsigned)pk0[i]) >> 16;
      int s1 = pk1[i] & 0xffff, c1 = ((unsigned)pk1[i]) >> 16;
      int s2 = pk2[i] & 0xffff, c2 = ((unsigned)pk2[i]) >> 16;
      float2 P0 = sP[c0], P1 = sP[c1], P2 = sP[c2];
      float2 t0 = sT[s0], t1 = sT[s1], t2 = sT[s2];
      float2 L = Ln[i];
      float ax = L.x + atanh2c(P0.x, t0.x) + atanh2c(P1.x, t1.x) + atanh2c(P2.x, t2.x);
      float ay = L.y + atanh2c(P0.y, t0.y) + atanh2c(P1.y, t1.y) + atanh2c(P2.y, t2.y);
      o0[n] = (ax < 0.0f) ? 1.0f : 0.0f;
      o1[n] = (ay < 0.0f) ? 1.0f : 0.0f;
    }
  }
}

// ---------------- launcher ----------------
extern "C" void kernel_launch(void* const* d_in, const int* in_sizes, int n_in,
                              void* d_out, int out_size, void* d_ws, size_t ws_size,
                              hipStream_t stream) {
  const float* ebno = (const float*)d_in[1];
  const int*   b    = (const int*)d_in[2];
  const int*   P    = (const int*)d_in[3];
  const int*   cn   = (const int*)d_in[4];
  const int*   vn   = (const int*)d_in[5];
  const float* h_re = (const float*)d_in[6];
  const float* h_im = (const float*)d_in[7];
  const float* nre  = (const float*)d_in[8];
  const float* nim  = (const float*)d_in[9];
  float* out = (float*)d_out;

  int E     = in_sizes[4];
  int batch = in_sizes[2] / (4 * KK);
  int ncw   = batch * 4;

  char* ws = (char*)d_ws;
  size_t off = 0;
  auto alloc = [&](size_t bytes) -> void* {
    void* p = ws + off;
    off += (bytes + 255) & ~(size_t)255;
    return p;
  };
  unsigned* Ppack  = (unsigned*)alloc((size_t)MM * 16 * 4);
  unsigned* bpack  = (unsigned*)alloc((size_t)ncw * 16 * 4);
  int*      coff   = (int*)alloc((size_t)(MM + 1) * 4);
  int*      cdend  = (int*)alloc((size_t)MM * 4);
  int*      cperm  = (int*)alloc((size_t)MM * 4);
  int*      cinfo  = (int*)alloc((size_t)EMAX * 4);
  int*      vlist  = (int*)alloc((size_t)NNODES * MAXVDEG * 4);
  double*   nobuf  = (double*)alloc(2 * 8);
  (void)ws_size; (void)n_in; (void)out_size;

  int packItems  = MM * 16 + ncw * 16;
  int packBlocks = (packItems + 511) / 512;
  int bfBlocks   = (ncw * KK + 511) / 512;
  int setupGrid  = 1 + packBlocks + bfBlocks;

  k_setup<<<dim3(setupGrid), dim3(512), 0, stream>>>(cn, vn, E, ebno, P, b, ncw,
                                                     cinfo, vlist, coff, cdend, cperm,
                                                     nobuf, Ppack, bpack, out, packBlocks);
  k_fused<<<dim3(ncw / 2), dim3(256), 0, stream>>>(h_re, h_im, nre, nim, nobuf,
                                                   bpack, Ppack, vlist, coff, cdend,
                                                   cperm, cinfo, out, ncw);
}